// Round 2
// baseline (7656.690 us; speedup 1.0000x reference)
//
#include <hip/hip_runtime.h>
#include <hip/hip_bf16.h>
#include <math.h>

// ---------------------------------------------------------------------------
// DiT block: B=4 L=2048 D=1024 H=16 HD=64 MLP=4096.
// I/O fp32 (per reference); internal activations/weights bf16 for MFMA,
// accumulation fp32. Workspace layout (bytes), total ~164 MB:
//   WqkvT  [3072][1024] bf16 @ 0
//   WprojT [1024][1024] bf16 @ 6291456
//   W1T    [4096][1024] bf16 @ 8388608
//   W2T    [1024][4096] bf16 @ 16777216
//   WtT    [6144][1024] bf16 @ 25165824
//   tp     [4][6144]    f32  @ 37748736
//   h      [8192][1024] bf16 @ 37847040   (LN1 out, later LN2 out)
//   qkv    [8192][3072] bf16 @ 54624256   } overlaid: mid [8192][4096] bf16
//   mid    ................. @ 54624256   } (qkv dead after attention)
//   attn   [8192][1024] bf16 @ 121733120
//   x1     [8192][1024] f32  @ 138510336
// ---------------------------------------------------------------------------

typedef __attribute__((ext_vector_type(8))) __bf16 bf16x8;
typedef __attribute__((ext_vector_type(4))) float f32x4;

union FragU { uint4 u; bf16x8 b; };

__device__ __forceinline__ float bflo(uint u) {
    union { uint i; float f; } v; v.i = u << 16; return v.f;
}
__device__ __forceinline__ float bfhi(uint u) {
    union { uint i; float f; } v; v.i = u & 0xffff0000u; return v.f;
}
__device__ __forceinline__ ushort f2bf(float f) {
    union { float f; uint i; } v; v.f = f;
    uint r = (v.i + 0x7fffu + ((v.i >> 16) & 1u)) >> 16;
    return (ushort)r;
}
__device__ __forceinline__ void stval(ushort* p, float v) { *p = f2bf(v); }
__device__ __forceinline__ void stval(float* p, float v) { *p = v; }

// ---------------------------------------------------------------------------
// Transpose + fp32->bf16: in [R][C] f32 -> out [C][R] bf16. Dims mult of 32.
// ---------------------------------------------------------------------------
__global__ __launch_bounds__(256) void transpose_f2b(const float* __restrict__ in,
                                                     ushort* __restrict__ out,
                                                     int R, int C) {
    __shared__ ushort t[32][33];
    int c0 = blockIdx.x * 32, r0 = blockIdx.y * 32;
    int tx = threadIdx.x, ty = threadIdx.y;  // block (32, 8)
#pragma unroll
    for (int i = 0; i < 32; i += 8)
        t[ty + i][tx] = f2bf(in[(size_t)(r0 + ty + i) * C + c0 + tx]);
    __syncthreads();
#pragma unroll
    for (int i = 0; i < 32; i += 8)
        out[(size_t)(c0 + ty + i) * R + r0 + tx] = t[tx][ty + i];
}

// ---------------------------------------------------------------------------
// tp = silu(time_emb) @ Wt + bt.  One wave per output element (b, n).
// te [4][1024] f32, WtT [6144][1024] bf16, bt f32, tp [4][6144] f32.
// ---------------------------------------------------------------------------
__global__ __launch_bounds__(256) void tp_gemm(const float* __restrict__ te,
                                               const ushort* __restrict__ WtT,
                                               const float* __restrict__ bt,
                                               float* __restrict__ tp) {
    int w = blockIdx.x * 4 + (threadIdx.x >> 6);
    int lane = threadIdx.x & 63;
    int b = w / 6144, n = w % 6144;
    const ushort* wr = WtT + (size_t)n * 1024;
    const float* tr = te + (size_t)b * 1024;
    float s = 0.f;
#pragma unroll
    for (int i = 0; i < 16; i++) {
        int k = lane + 64 * i;
        float t = tr[k];
        float sil = t / (1.f + __expf(-t));
        s += sil * bflo((uint)wr[k]);
    }
#pragma unroll
    for (int x = 32; x; x >>= 1) s += __shfl_xor(s, x);
    if (lane == 0) tp[(size_t)b * 6144 + n] = s + bt[n];
}

// ---------------------------------------------------------------------------
// Fused LayerNorm + AdaLN modulate: out = (ln(x)*g+be)*(1+scale)+shift.
// x fp32 [8192][1024]; out bf16. One block per row, 256 thr x 4 elems.
// ---------------------------------------------------------------------------
__global__ __launch_bounds__(256) void ln_mod(const float* __restrict__ x,
                                              const float* __restrict__ tpb,
                                              const float* __restrict__ g,
                                              const float* __restrict__ be,
                                              ushort* __restrict__ out,
                                              int shift_off, int scale_off) {
    __shared__ float2 sred[4];
    int row = blockIdx.x;
    int b = row >> 11;
    int tid = threadIdx.x;
    float4 f = *(const float4*)&x[(size_t)row * 1024 + tid * 4];
    float v[4] = {f.x, f.y, f.z, f.w};
    float s = v[0] + v[1] + v[2] + v[3];
    float s2 = v[0] * v[0] + v[1] * v[1] + v[2] * v[2] + v[3] * v[3];
#pragma unroll
    for (int m = 32; m; m >>= 1) { s += __shfl_xor(s, m); s2 += __shfl_xor(s2, m); }
    if ((tid & 63) == 0) sred[tid >> 6] = make_float2(s, s2);
    __syncthreads();
    s = sred[0].x + sred[1].x + sred[2].x + sred[3].x;
    s2 = sred[0].y + sred[1].y + sred[2].y + sred[3].y;
    float mu = s * (1.f / 1024.f);
    float var = s2 * (1.f / 1024.f) - mu * mu;
    float rs = rsqrtf(var + 1e-5f);
    const float* tprow = tpb + (size_t)b * 6144;
    ushort o4[4];
#pragma unroll
    for (int t = 0; t < 4; t++) {
        int c = tid * 4 + t;
        float y = (v[t] - mu) * rs * g[c] + be[c];
        y = y * (1.f + tprow[scale_off + c]) + tprow[shift_off + c];
        o4[t] = f2bf(y);
    }
    *(uint2*)&out[(size_t)row * 1024 + tid * 4] = *(uint2*)o4;
}

// ---------------------------------------------------------------------------
// MFMA bf16 GEMM: C[M][N] = A[M][K] @ B + bias, B given transposed BT[N][K].
// 128x128 tile, BK=32, 256 threads = 4 waves (2x2), each wave 4x4 16x16 tiles.
// EPI 0: C = acc+bias               EPI 1: C = gelu_exact(acc+bias)
// EPI 2: C = res + gate[b][col]*(acc+bias),  gate = tp[b][goff+col]
// ---------------------------------------------------------------------------
template <int EPI, typename OT>
__global__ __launch_bounds__(256) void gemm_bt(const ushort* __restrict__ A,
                                               const ushort* __restrict__ BT,
                                               const float* __restrict__ bias,
                                               OT* __restrict__ C,
                                               int M, int N, int K,
                                               const float* __restrict__ res,
                                               const float* __restrict__ tpb,
                                               int goff) {
    __shared__ __align__(16) ushort As[128 * 32];
    __shared__ __align__(16) ushort Bs[128 * 32];
    int m0 = blockIdx.y * 128, n0 = blockIdx.x * 128;
    int tid = threadIdx.x;
    int wid = tid >> 6, lane = tid & 63;
    int wy = wid >> 1, wx = wid & 1;
    int r16 = lane & 15;
    int q8 = (lane >> 4) << 3;

    f32x4 acc[4][4];
#pragma unroll
    for (int i = 0; i < 4; i++)
#pragma unroll
        for (int j = 0; j < 4; j++) acc[i][j] = (f32x4){0.f, 0.f, 0.f, 0.f};

    int sr = tid >> 2;            // 0..63
    int sc = (tid & 3) << 3;      // 0,8,16,24
    const ushort* Abase = A + (size_t)(m0 + sr) * K + sc;
    const ushort* Bbase = BT + (size_t)(n0 + sr) * K + sc;

    for (int k0 = 0; k0 < K; k0 += 32) {
        *(uint4*)&As[sr * 32 + sc] = *(const uint4*)(Abase + k0);
        *(uint4*)&As[(sr + 64) * 32 + sc] = *(const uint4*)(Abase + (size_t)64 * K + k0);
        *(uint4*)&Bs[sr * 32 + sc] = *(const uint4*)(Bbase + k0);
        *(uint4*)&Bs[(sr + 64) * 32 + sc] = *(const uint4*)(Bbase + (size_t)64 * K + k0);
        __syncthreads();
        FragU fa[4], fb[4];
#pragma unroll
        for (int i = 0; i < 4; i++)
            fa[i].u = *(const uint4*)&As[(wy * 64 + i * 16 + r16) * 32 + q8];
#pragma unroll
        for (int j = 0; j < 4; j++)
            fb[j].u = *(const uint4*)&Bs[(wx * 64 + j * 16 + r16) * 32 + q8];
#pragma unroll
        for (int i = 0; i < 4; i++)
#pragma unroll
            for (int j = 0; j < 4; j++)
                acc[i][j] = __builtin_amdgcn_mfma_f32_16x16x32_bf16(fa[i].b, fb[j].b, acc[i][j], 0, 0, 0);
        __syncthreads();
    }

    int q4 = (lane >> 4) << 2;
#pragma unroll
    for (int i = 0; i < 4; i++) {
#pragma unroll
        for (int j = 0; j < 4; j++) {
            int col = n0 + wx * 64 + j * 16 + r16;
            float bv = bias[col];
#pragma unroll
            for (int t = 0; t < 4; t++) {
                int row = m0 + wy * 64 + i * 16 + q4 + t;
                float v = acc[i][j][t] + bv;
                if constexpr (EPI == 1) {
                    v = 0.5f * v * (1.f + erff(v * 0.70710678118f));
                }
                if constexpr (EPI == 2) {
                    float rv = res[(size_t)row * N + col];
                    float gate = tpb[(size_t)(row >> 11) * 6144 + goff + col];
                    v = rv + gate * v;
                }
                stval(&C[(size_t)row * N + col], v);
            }
        }
    }
}

// ---------------------------------------------------------------------------
// Flash attention, one wave per (b, h, l) row. qkv [8192][3072] bf16 packed
// as [q(16 heads x 64) | k | v].  out [8192][1024] bf16 (head-major cols).
// Lane-per-key online softmax; LDS transpose-reduce of o at the end.
// ---------------------------------------------------------------------------
__global__ __launch_bounds__(256) void attn_kernel(const ushort* __restrict__ qkv,
                                                   ushort* __restrict__ out) {
    __shared__ float red[4][64][16];  // 16 KB
    int wid = threadIdx.x >> 6, lane = threadIdx.x & 63;
    int bh = blockIdx.x >> 9;                    // 0..63
    int l = ((blockIdx.x & 511) << 2) + wid;     // 0..2047
    int b = bh >> 4, h = bh & 15;

    const ushort* base = qkv + (size_t)b * 2048 * 3072 + h * 64;
    const ushort* qr = base + (size_t)l * 3072;
    float q[64];
#pragma unroll
    for (int i = 0; i < 8; i++) {
        uint4 u = *(const uint4*)&qr[i * 8];
        q[i * 8 + 0] = bflo(u.x) * 0.125f; q[i * 8 + 1] = bfhi(u.x) * 0.125f;
        q[i * 8 + 2] = bflo(u.y) * 0.125f; q[i * 8 + 3] = bfhi(u.y) * 0.125f;
        q[i * 8 + 4] = bflo(u.z) * 0.125f; q[i * 8 + 5] = bfhi(u.z) * 0.125f;
        q[i * 8 + 6] = bflo(u.w) * 0.125f; q[i * 8 + 7] = bfhi(u.w) * 0.125f;
    }
    float m = -1e30f, lsum = 0.f;
    float o[64];
#pragma unroll
    for (int d = 0; d < 64; d++) o[d] = 0.f;

    const ushort* kb = base + 1024;
    const ushort* vb = base + 2048;
    for (int j0 = 0; j0 < 2048; j0 += 64) {
        const ushort* kr = kb + (size_t)(j0 + lane) * 3072;
        float s = 0.f;
#pragma unroll
        for (int i = 0; i < 8; i++) {
            uint4 u = *(const uint4*)&kr[i * 8];
            s += q[i * 8 + 0] * bflo(u.x) + q[i * 8 + 1] * bfhi(u.x);
            s += q[i * 8 + 2] * bflo(u.y) + q[i * 8 + 3] * bfhi(u.y);
            s += q[i * 8 + 4] * bflo(u.z) + q[i * 8 + 5] * bfhi(u.z);
            s += q[i * 8 + 6] * bflo(u.w) + q[i * 8 + 7] * bfhi(u.w);
        }
        if (s > m) {
            float al = __expf(m - s);
            lsum *= al;
#pragma unroll
            for (int d = 0; d < 64; d++) o[d] *= al;
            m = s;
        }
        float p = __expf(s - m);
        lsum += p;
        const ushort* vr = vb + (size_t)(j0 + lane) * 3072;
#pragma unroll
        for (int i = 0; i < 8; i++) {
            uint4 u = *(const uint4*)&vr[i * 8];
            o[i * 8 + 0] += p * bflo(u.x); o[i * 8 + 1] += p * bfhi(u.x);
            o[i * 8 + 2] += p * bflo(u.y); o[i * 8 + 3] += p * bfhi(u.y);
            o[i * 8 + 4] += p * bflo(u.z); o[i * 8 + 5] += p * bfhi(u.z);
            o[i * 8 + 6] += p * bflo(u.w); o[i * 8 + 7] += p * bfhi(u.w);
        }
    }

    // merge lanes: global max, global sum, weighted o reduce
    float M = m;
#pragma unroll
    for (int x = 32; x; x >>= 1) M = fmaxf(M, __shfl_xor(M, x));
    float sc = __expf(m - M);
    float L = lsum * sc;
#pragma unroll
    for (int x = 32; x; x >>= 1) L += __shfl_xor(L, x);
    float inv = 1.f / L;

    ushort* orow = out + (size_t)(b * 2048 + l) * 1024 + h * 64;
    int t16 = lane & 15, g4 = lane >> 4;
    for (int c = 0; c < 4; c++) {
#pragma unroll
        for (int t = 0; t < 16; t++) red[wid][lane][t] = o[c * 16 + t] * sc;
        __syncthreads();
        float ps = 0.f;
#pragma unroll
        for (int r = 0; r < 16; r++) ps += red[wid][g4 * 16 + r][t16];
        ps += __shfl_xor(ps, 16);
        ps += __shfl_xor(ps, 32);
        if (lane < 16) orow[c * 16 + lane] = f2bf(ps * inv);
        __syncthreads();
    }
}

// ---------------------------------------------------------------------------
extern "C" void kernel_launch(void* const* d_in, const int* in_sizes, int n_in,
                              void* d_out, int out_size, void* d_ws, size_t ws_size,
                              hipStream_t stream) {
    const float* x    = (const float*)d_in[0];
    const float* te   = (const float*)d_in[1];
    const float* Wqkv = (const float*)d_in[2];
    const float* bqkv = (const float*)d_in[3];
    const float* Wproj= (const float*)d_in[4];
    const float* bproj= (const float*)d_in[5];
    const float* W1   = (const float*)d_in[6];
    const float* b1   = (const float*)d_in[7];
    const float* W2   = (const float*)d_in[8];
    const float* b2   = (const float*)d_in[9];
    const float* Wt   = (const float*)d_in[10];
    const float* bt   = (const float*)d_in[11];
    const float* g1   = (const float*)d_in[12];
    const float* be1  = (const float*)d_in[13];
    const float* g2   = (const float*)d_in[14];
    const float* be2  = (const float*)d_in[15];

    char* ws = (char*)d_ws;
    ushort* WqkvT  = (ushort*)(ws + 0);
    ushort* WprojT = (ushort*)(ws + 6291456);
    ushort* W1T    = (ushort*)(ws + 8388608);
    ushort* W2T    = (ushort*)(ws + 16777216);
    ushort* WtT    = (ushort*)(ws + 25165824);
    float*  tpb    = (float*)(ws + 37748736);
    ushort* hbuf   = (ushort*)(ws + 37847040);
    ushort* qkvb   = (ushort*)(ws + 54624256);
    ushort* midb   = (ushort*)(ws + 54624256);   // overlays qkv (dead by then)
    ushort* attnb  = (ushort*)(ws + 121733120);
    float*  x1b    = (float*)(ws + 138510336);

    dim3 tb(32, 8);
    hipLaunchKernelGGL(transpose_f2b, dim3(3072 / 32, 1024 / 32), tb, 0, stream, Wqkv, WqkvT, 1024, 3072);
    hipLaunchKernelGGL(transpose_f2b, dim3(1024 / 32, 1024 / 32), tb, 0, stream, Wproj, WprojT, 1024, 1024);
    hipLaunchKernelGGL(transpose_f2b, dim3(4096 / 32, 1024 / 32), tb, 0, stream, W1, W1T, 1024, 4096);
    hipLaunchKernelGGL(transpose_f2b, dim3(1024 / 32, 4096 / 32), tb, 0, stream, W2, W2T, 4096, 1024);
    hipLaunchKernelGGL(transpose_f2b, dim3(6144 / 32, 1024 / 32), tb, 0, stream, Wt, WtT, 1024, 6144);

    hipLaunchKernelGGL(tp_gemm, dim3(6144), dim3(256), 0, stream, te, WtT, bt, tpb);

    // LN1 + modulate (shift_msa @0, scale_msa @1024)
    hipLaunchKernelGGL(ln_mod, dim3(8192), dim3(256), 0, stream, x, tpb, g1, be1, hbuf, 0, 1024);

    // qkv = h @ Wqkv + bqkv
    hipLaunchKernelGGL((gemm_bt<0, ushort>), dim3(3072 / 128, 8192 / 128), dim3(256), 0, stream,
                       hbuf, WqkvT, bqkv, qkvb, 8192, 3072, 1024, (const float*)nullptr, (const float*)nullptr, 0);

    hipLaunchKernelGGL(attn_kernel, dim3(32768), dim3(256), 0, stream, qkvb, attnb);

    // x1 = x + gate_msa * (attn @ Wproj + bproj)   (gate_msa @2048)
    hipLaunchKernelGGL((gemm_bt<2, float>), dim3(1024 / 128, 8192 / 128), dim3(256), 0, stream,
                       attnb, WprojT, bproj, x1b, 8192, 1024, 1024, x, tpb, 2048);

    // LN2 + modulate (shift_mlp @3072, scale_mlp @4096)
    hipLaunchKernelGGL(ln_mod, dim3(8192), dim3(256), 0, stream, x1b, tpb, g2, be2, hbuf, 3072, 4096);

    // mid = gelu(h @ W1 + b1)
    hipLaunchKernelGGL((gemm_bt<1, ushort>), dim3(4096 / 128, 8192 / 128), dim3(256), 0, stream,
                       hbuf, W1T, b1, midb, 8192, 4096, 1024, (const float*)nullptr, (const float*)nullptr, 0);

    // out = x1 + gate_mlp * (mid @ W2 + b2)   (gate_mlp @5120)
    hipLaunchKernelGGL((gemm_bt<2, float>), dim3(1024 / 128, 8192 / 128), dim3(256), 0, stream,
                       midb, W2T, b2, (float*)d_out, 8192, 1024, 4096, x1b, tpb, 5120);
}

// Round 3
// 890.928 us; speedup vs baseline: 8.5941x; 8.5941x over previous
//
#include <hip/hip_runtime.h>
#include <hip/hip_bf16.h>
#include <math.h>

// ---------------------------------------------------------------------------
// DiT block: B=4 L=2048 D=1024 H=16 HD=64 MLP=4096.
// I/O fp32 (per reference); internal activations/weights bf16 for MFMA,
// accumulation fp32. Workspace layout (bytes), total ~164 MB:
//   WqkvT  [3072][1024] bf16 @ 0
//   WprojT [1024][1024] bf16 @ 6291456
//   W1T    [4096][1024] bf16 @ 8388608
//   W2T    [1024][4096] bf16 @ 16777216
//   WtT    [6144][1024] bf16 @ 25165824
//   tp     [4][6144]    f32  @ 37748736
//   h      [8192][1024] bf16 @ 37847040   (LN1 out, later LN2 out)
//   qkv    [8192][3072] bf16 @ 54624256   } overlaid: mid [8192][4096] bf16
//   mid    ................. @ 54624256   } (qkv dead after attention)
//   attn   [8192][1024] bf16 @ 121733120
//   x1     [8192][1024] f32  @ 138510336
// ---------------------------------------------------------------------------

typedef __attribute__((ext_vector_type(8))) __bf16 bf16x8;
typedef __attribute__((ext_vector_type(4))) float f32x4;

union FragU { uint4 u; bf16x8 b; };

__device__ __forceinline__ float bflo(uint u) {
    union { uint i; float f; } v; v.i = u << 16; return v.f;
}
__device__ __forceinline__ ushort f2bf(float f) {
    union { float f; uint i; } v; v.f = f;
    uint r = (v.i + 0x7fffu + ((v.i >> 16) & 1u)) >> 16;
    return (ushort)r;
}
__device__ __forceinline__ void stval(ushort* p, float v) { *p = f2bf(v); }
__device__ __forceinline__ void stval(float* p, float v) { *p = v; }

// ---------------------------------------------------------------------------
// Transpose + fp32->bf16: in [R][C] f32 -> out [C][R] bf16. Dims mult of 32.
// ---------------------------------------------------------------------------
__global__ __launch_bounds__(256) void transpose_f2b(const float* __restrict__ in,
                                                     ushort* __restrict__ out,
                                                     int R, int C) {
    __shared__ ushort t[32][33];
    int c0 = blockIdx.x * 32, r0 = blockIdx.y * 32;
    int tx = threadIdx.x, ty = threadIdx.y;  // block (32, 8)
#pragma unroll
    for (int i = 0; i < 32; i += 8)
        t[ty + i][tx] = f2bf(in[(size_t)(r0 + ty + i) * C + c0 + tx]);
    __syncthreads();
#pragma unroll
    for (int i = 0; i < 32; i += 8)
        out[(size_t)(c0 + ty + i) * R + r0 + tx] = t[tx][ty + i];
}

// ---------------------------------------------------------------------------
// tp = silu(time_emb) @ Wt + bt.  One wave per output element (b, n).
// ---------------------------------------------------------------------------
__global__ __launch_bounds__(256) void tp_gemm(const float* __restrict__ te,
                                               const ushort* __restrict__ WtT,
                                               const float* __restrict__ bt,
                                               float* __restrict__ tp) {
    int w = blockIdx.x * 4 + (threadIdx.x >> 6);
    int lane = threadIdx.x & 63;
    int b = w / 6144, n = w % 6144;
    const ushort* wr = WtT + (size_t)n * 1024;
    const float* tr = te + (size_t)b * 1024;
    float s = 0.f;
#pragma unroll
    for (int i = 0; i < 16; i++) {
        int k = lane + 64 * i;
        float t = tr[k];
        float sil = t / (1.f + __expf(-t));
        s += sil * bflo((uint)wr[k]);
    }
#pragma unroll
    for (int x = 32; x; x >>= 1) s += __shfl_xor(s, x);
    if (lane == 0) tp[(size_t)b * 6144 + n] = s + bt[n];
}

// ---------------------------------------------------------------------------
// Fused LayerNorm + AdaLN modulate: out = (ln(x)*g+be)*(1+scale)+shift.
// ---------------------------------------------------------------------------
__global__ __launch_bounds__(256) void ln_mod(const float* __restrict__ x,
                                              const float* __restrict__ tpb,
                                              const float* __restrict__ g,
                                              const float* __restrict__ be,
                                              ushort* __restrict__ out,
                                              int shift_off, int scale_off) {
    __shared__ float2 sred[4];
    int row = blockIdx.x;
    int b = row >> 11;
    int tid = threadIdx.x;
    float4 f = *(const float4*)&x[(size_t)row * 1024 + tid * 4];
    float v[4] = {f.x, f.y, f.z, f.w};
    float s = v[0] + v[1] + v[2] + v[3];
    float s2 = v[0] * v[0] + v[1] * v[1] + v[2] * v[2] + v[3] * v[3];
#pragma unroll
    for (int m = 32; m; m >>= 1) { s += __shfl_xor(s, m); s2 += __shfl_xor(s2, m); }
    if ((tid & 63) == 0) sred[tid >> 6] = make_float2(s, s2);
    __syncthreads();
    s = sred[0].x + sred[1].x + sred[2].x + sred[3].x;
    s2 = sred[0].y + sred[1].y + sred[2].y + sred[3].y;
    float mu = s * (1.f / 1024.f);
    float var = s2 * (1.f / 1024.f) - mu * mu;
    float rs = rsqrtf(var + 1e-5f);
    const float* tprow = tpb + (size_t)b * 6144;
    ushort o4[4];
#pragma unroll
    for (int t = 0; t < 4; t++) {
        int c = tid * 4 + t;
        float y = (v[t] - mu) * rs * g[c] + be[c];
        y = y * (1.f + tprow[scale_off + c]) + tprow[shift_off + c];
        o4[t] = f2bf(y);
    }
    *(uint2*)&out[(size_t)row * 1024 + tid * 4] = *(uint2*)o4;
}

// ---------------------------------------------------------------------------
// MFMA bf16 GEMM: C[M][N] = A[M][K] @ B + bias, B given transposed BT[N][K].
// 128x128 tile, BK=32, 4 waves (2x2), each wave 4x4 16x16 tiles.
// EPI 0: C = acc+bias               EPI 1: C = gelu_exact(acc+bias)
// EPI 2: C = res + gate[b][col]*(acc+bias),  gate = tp[b][goff+col]
// ---------------------------------------------------------------------------
template <int EPI, typename OT>
__global__ __launch_bounds__(256) void gemm_bt(const ushort* __restrict__ A,
                                               const ushort* __restrict__ BT,
                                               const float* __restrict__ bias,
                                               OT* __restrict__ C,
                                               int M, int N, int K,
                                               const float* __restrict__ res,
                                               const float* __restrict__ tpb,
                                               int goff) {
    __shared__ __align__(16) ushort As[128 * 32];
    __shared__ __align__(16) ushort Bs[128 * 32];
    int m0 = blockIdx.y * 128, n0 = blockIdx.x * 128;
    int tid = threadIdx.x;
    int wid = tid >> 6, lane = tid & 63;
    int wy = wid >> 1, wx = wid & 1;
    int r16 = lane & 15;
    int q8 = (lane >> 4) << 3;

    f32x4 acc[4][4];
#pragma unroll
    for (int i = 0; i < 4; i++)
#pragma unroll
        for (int j = 0; j < 4; j++) acc[i][j] = (f32x4){0.f, 0.f, 0.f, 0.f};

    int sr = tid >> 2;            // 0..63
    int sc = (tid & 3) << 3;      // 0,8,16,24
    const ushort* Abase = A + (size_t)(m0 + sr) * K + sc;
    const ushort* Bbase = BT + (size_t)(n0 + sr) * K + sc;

    for (int k0 = 0; k0 < K; k0 += 32) {
        *(uint4*)&As[sr * 32 + sc] = *(const uint4*)(Abase + k0);
        *(uint4*)&As[(sr + 64) * 32 + sc] = *(const uint4*)(Abase + (size_t)64 * K + k0);
        *(uint4*)&Bs[sr * 32 + sc] = *(const uint4*)(Bbase + k0);
        *(uint4*)&Bs[(sr + 64) * 32 + sc] = *(const uint4*)(Bbase + (size_t)64 * K + k0);
        __syncthreads();
        FragU fa[4], fb[4];
#pragma unroll
        for (int i = 0; i < 4; i++)
            fa[i].u = *(const uint4*)&As[(wy * 64 + i * 16 + r16) * 32 + q8];
#pragma unroll
        for (int j = 0; j < 4; j++)
            fb[j].u = *(const uint4*)&Bs[(wx * 64 + j * 16 + r16) * 32 + q8];
#pragma unroll
        for (int i = 0; i < 4; i++)
#pragma unroll
            for (int j = 0; j < 4; j++)
                acc[i][j] = __builtin_amdgcn_mfma_f32_16x16x32_bf16(fa[i].b, fb[j].b, acc[i][j], 0, 0, 0);
        __syncthreads();
    }

    int q4 = (lane >> 4) << 2;
#pragma unroll
    for (int i = 0; i < 4; i++) {
#pragma unroll
        for (int j = 0; j < 4; j++) {
            int col = n0 + wx * 64 + j * 16 + r16;
            float bv = bias[col];
#pragma unroll
            for (int t = 0; t < 4; t++) {
                int row = m0 + wy * 64 + i * 16 + q4 + t;
                float v = acc[i][j][t] + bv;
                if constexpr (EPI == 1) {
                    v = 0.5f * v * (1.f + erff(v * 0.70710678118f));
                }
                if constexpr (EPI == 2) {
                    float rv = res[(size_t)row * N + col];
                    float gate = tpb[(size_t)(row >> 11) * 6144 + goff + col];
                    v = rv + gate * v;
                }
                stval(&C[(size_t)row * N + col], v);
            }
        }
    }
}

// ---------------------------------------------------------------------------
// MFMA flash attention. qkv [8192][3072] bf16, packed [q|k|v] x 16 heads x 64.
// Grid: 1024 blocks = 64 (b,h) x 16 q-tiles of 128 rows. 256 thr = 4 waves,
// each wave owns 32 q-rows (2 x 16). K-loop over 64-key tiles:
//   S = Q K^T via mfma (K rows are the B^T operand directly)
//   online softmax in C-layout regs (row = quad*4+t), 16-lane shfl reduces
//   P -> per-wave-private LDS (C-layout -> A-layout transform)
//   O += P V via mfma (V staged transposed: Vs[d][key])
// LDS: Ks[64][72] + Vs[64][72] + Ps[128][72] = 36 KB -> 4 blocks/CU.
// ---------------------------------------------------------------------------
__global__ __launch_bounds__(256) void attn_mfma(const ushort* __restrict__ qkv,
                                                 ushort* __restrict__ out) {
    __shared__ __align__(16) ushort Ks[64 * 72];
    __shared__ __align__(16) ushort Vs[64 * 72];
    __shared__ __align__(16) ushort Ps[128 * 72];   // Q staging in phase 0

    int tid = threadIdx.x;
    int wid = tid >> 6, lane = tid & 63;
    int r16 = lane & 15, quad = lane >> 4;
    int q8 = quad << 3, q4 = quad << 2;

    int bh = blockIdx.x >> 4;        // 0..63
    int qt = blockIdx.x & 15;        // 0..15
    int b = bh >> 4, h = bh & 15;
    const ushort* qkbase = qkv + (size_t)b * 2048 * 3072 + h * 64;

    // ---- phase 0: stage Q tile [128][64] into Ps region, load A-frags ----
    {
        int r = tid >> 2;                 // 0..63
        int c = (tid & 3) << 4;           // 0,16,32,48
        const ushort* qp = qkbase + (size_t)(qt * 128 + r) * 3072 + c;
        *(uint4*)&Ps[r * 72 + c] = *(const uint4*)qp;
        *(uint4*)&Ps[r * 72 + c + 8] = *(const uint4*)(qp + 8);
        qp += (size_t)64 * 3072;
        *(uint4*)&Ps[(r + 64) * 72 + c] = *(const uint4*)qp;
        *(uint4*)&Ps[(r + 64) * 72 + c + 8] = *(const uint4*)(qp + 8);
    }
    __syncthreads();
    FragU qa[2][2];
#pragma unroll
    for (int i = 0; i < 2; i++)
#pragma unroll
        for (int ks = 0; ks < 2; ks++)
            qa[i][ks].u = *(const uint4*)&Ps[(wid * 32 + i * 16 + r16) * 72 + ks * 32 + q8];
    // After this, each wave only writes/reads its own 32 Ps rows (private).

    float m_[2][4], l_[2][4];
    f32x4 o[2][4];
#pragma unroll
    for (int i = 0; i < 2; i++)
#pragma unroll
        for (int t = 0; t < 4; t++) { m_[i][t] = -1e30f; l_[i][t] = 0.f; }
#pragma unroll
    for (int i = 0; i < 2; i++)
#pragma unroll
        for (int dn = 0; dn < 4; dn++) o[i][dn] = (f32x4){0.f, 0.f, 0.f, 0.f};

    int kr = tid >> 2;                    // K-stage row 0..63
    int kc = (tid & 3) << 4;              // 0,16,32,48
    int vk = (tid & 31) << 1;             // V keys 0,2,..,62
    int vd = (tid >> 5) << 3;             // V d 0,8,..,56

    for (int kt = 0; kt < 32; kt++) {
        __syncthreads();   // prior iteration's Ks/Vs readers done (incl. Q-frag phase)
        // stage K tile [key][d]
        {
            const ushort* kp = qkbase + 1024 + (size_t)(kt * 64 + kr) * 3072 + kc;
            *(uint4*)&Ks[kr * 72 + kc] = *(const uint4*)kp;
            *(uint4*)&Ks[kr * 72 + kc + 8] = *(const uint4*)(kp + 8);
        }
        // stage V transposed: Vs[d][key], pair-packed uint writes
        {
            const ushort* vp = qkbase + 2048 + (size_t)(kt * 64 + vk) * 3072 + vd;
            uint4 v0 = *(const uint4*)vp;
            uint4 v1 = *(const uint4*)(vp + 3072);
            *(uint*)&Vs[(vd + 0) * 72 + vk] = (v0.x & 0xffffu) | (v1.x << 16);
            *(uint*)&Vs[(vd + 1) * 72 + vk] = (v0.x >> 16) | (v1.x & 0xffff0000u);
            *(uint*)&Vs[(vd + 2) * 72 + vk] = (v0.y & 0xffffu) | (v1.y << 16);
            *(uint*)&Vs[(vd + 3) * 72 + vk] = (v0.y >> 16) | (v1.y & 0xffff0000u);
            *(uint*)&Vs[(vd + 4) * 72 + vk] = (v0.z & 0xffffu) | (v1.z << 16);
            *(uint*)&Vs[(vd + 5) * 72 + vk] = (v0.z >> 16) | (v1.z & 0xffff0000u);
            *(uint*)&Vs[(vd + 6) * 72 + vk] = (v0.w & 0xffffu) | (v1.w << 16);
            *(uint*)&Vs[(vd + 7) * 72 + vk] = (v0.w >> 16) | (v1.w & 0xffff0000u);
        }
        __syncthreads();

        // ---- S = Q K^T * scale ----
        f32x4 s[2][4];
#pragma unroll
        for (int i = 0; i < 2; i++)
#pragma unroll
            for (int n = 0; n < 4; n++) s[i][n] = (f32x4){0.f, 0.f, 0.f, 0.f};
#pragma unroll
        for (int ks = 0; ks < 2; ks++) {
            FragU kb[4];
#pragma unroll
            for (int n = 0; n < 4; n++)
                kb[n].u = *(const uint4*)&Ks[(n * 16 + r16) * 72 + ks * 32 + q8];
#pragma unroll
            for (int i = 0; i < 2; i++)
#pragma unroll
                for (int n = 0; n < 4; n++)
                    s[i][n] = __builtin_amdgcn_mfma_f32_16x16x32_bf16(qa[i][ks].b, kb[n].b, s[i][n], 0, 0, 0);
        }
#pragma unroll
        for (int i = 0; i < 2; i++)
#pragma unroll
            for (int n = 0; n < 4; n++)
#pragma unroll
                for (int t = 0; t < 4; t++) s[i][n][t] *= 0.125f;

        // ---- online softmax (rows = quad*4+t, cols across 16 lanes x 4 n) ----
#pragma unroll
        for (int i = 0; i < 2; i++) {
            float nm[4], al[4];
#pragma unroll
            for (int t = 0; t < 4; t++) {
                float v0 = fmaxf(fmaxf(s[i][0][t], s[i][1][t]), fmaxf(s[i][2][t], s[i][3][t]));
#pragma unroll
                for (int msk = 1; msk < 16; msk <<= 1) v0 = fmaxf(v0, __shfl_xor(v0, msk));
                nm[t] = fmaxf(m_[i][t], v0);
                al[t] = __expf(m_[i][t] - nm[t]);
                m_[i][t] = nm[t];
            }
            float ps[4] = {0.f, 0.f, 0.f, 0.f};
#pragma unroll
            for (int n = 0; n < 4; n++)
#pragma unroll
                for (int t = 0; t < 4; t++) {
                    float p = __expf(s[i][n][t] - nm[t]);
                    ps[t] += p;
                    Ps[(wid * 32 + i * 16 + q4 + t) * 72 + n * 16 + r16] = f2bf(p);
                }
#pragma unroll
            for (int t = 0; t < 4; t++) {
#pragma unroll
                for (int msk = 1; msk < 16; msk <<= 1) ps[t] += __shfl_xor(ps[t], msk);
                l_[i][t] = l_[i][t] * al[t] + ps[t];
            }
#pragma unroll
            for (int dn = 0; dn < 4; dn++)
#pragma unroll
                for (int t = 0; t < 4; t++) o[i][dn][t] *= al[t];
        }

        // ---- O += P V  (Ps rows are wave-private: no barrier needed) ----
#pragma unroll
        for (int ks = 0; ks < 2; ks++) {
            FragU vb[4], pa[2];
#pragma unroll
            for (int dn = 0; dn < 4; dn++)
                vb[dn].u = *(const uint4*)&Vs[(dn * 16 + r16) * 72 + ks * 32 + q8];
#pragma unroll
            for (int i = 0; i < 2; i++)
                pa[i].u = *(const uint4*)&Ps[(wid * 32 + i * 16 + r16) * 72 + ks * 32 + q8];
#pragma unroll
            for (int i = 0; i < 2; i++)
#pragma unroll
                for (int dn = 0; dn < 4; dn++)
                    o[i][dn] = __builtin_amdgcn_mfma_f32_16x16x32_bf16(pa[i].b, vb[dn].b, o[i][dn], 0, 0, 0);
        }
    }

    // ---- epilogue: O / l -> out[row][h*64+d] ----
#pragma unroll
    for (int i = 0; i < 2; i++) {
        float inv[4];
#pragma unroll
        for (int t = 0; t < 4; t++) inv[t] = 1.f / l_[i][t];
#pragma unroll
        for (int dn = 0; dn < 4; dn++)
#pragma unroll
            for (int t = 0; t < 4; t++) {
                int row = qt * 128 + wid * 32 + i * 16 + q4 + t;
                out[(size_t)(b * 2048 + row) * 1024 + h * 64 + dn * 16 + r16] =
                    f2bf(o[i][dn][t] * inv[t]);
            }
    }
}

// ---------------------------------------------------------------------------
extern "C" void kernel_launch(void* const* d_in, const int* in_sizes, int n_in,
                              void* d_out, int out_size, void* d_ws, size_t ws_size,
                              hipStream_t stream) {
    const float* x    = (const float*)d_in[0];
    const float* te   = (const float*)d_in[1];
    const float* Wqkv = (const float*)d_in[2];
    const float* bqkv = (const float*)d_in[3];
    const float* Wproj= (const float*)d_in[4];
    const float* bproj= (const float*)d_in[5];
    const float* W1   = (const float*)d_in[6];
    const float* b1   = (const float*)d_in[7];
    const float* W2   = (const float*)d_in[8];
    const float* b2   = (const float*)d_in[9];
    const float* Wt   = (const float*)d_in[10];
    const float* bt   = (const float*)d_in[11];
    const float* g1   = (const float*)d_in[12];
    const float* be1  = (const float*)d_in[13];
    const float* g2   = (const float*)d_in[14];
    const float* be2  = (const float*)d_in[15];

    char* ws = (char*)d_ws;
    ushort* WqkvT  = (ushort*)(ws + 0);
    ushort* WprojT = (ushort*)(ws + 6291456);
    ushort* W1T    = (ushort*)(ws + 8388608);
    ushort* W2T    = (ushort*)(ws + 16777216);
    ushort* WtT    = (ushort*)(ws + 25165824);
    float*  tpb    = (float*)(ws + 37748736);
    ushort* hbuf   = (ushort*)(ws + 37847040);
    ushort* qkvb   = (ushort*)(ws + 54624256);
    ushort* midb   = (ushort*)(ws + 54624256);   // overlays qkv (dead by then)
    ushort* attnb  = (ushort*)(ws + 121733120);
    float*  x1b    = (float*)(ws + 138510336);

    dim3 tb(32, 8);
    hipLaunchKernelGGL(transpose_f2b, dim3(3072 / 32, 1024 / 32), tb, 0, stream, Wqkv, WqkvT, 1024, 3072);
    hipLaunchKernelGGL(transpose_f2b, dim3(1024 / 32, 1024 / 32), tb, 0, stream, Wproj, WprojT, 1024, 1024);
    hipLaunchKernelGGL(transpose_f2b, dim3(4096 / 32, 1024 / 32), tb, 0, stream, W1, W1T, 1024, 4096);
    hipLaunchKernelGGL(transpose_f2b, dim3(1024 / 32, 4096 / 32), tb, 0, stream, W2, W2T, 4096, 1024);
    hipLaunchKernelGGL(transpose_f2b, dim3(6144 / 32, 1024 / 32), tb, 0, stream, Wt, WtT, 1024, 6144);

    hipLaunchKernelGGL(tp_gemm, dim3(6144), dim3(256), 0, stream, te, WtT, bt, tpb);

    // LN1 + modulate (shift_msa @0, scale_msa @1024)
    hipLaunchKernelGGL(ln_mod, dim3(8192), dim3(256), 0, stream, x, tpb, g1, be1, hbuf, 0, 1024);

    // qkv = h @ Wqkv + bqkv
    hipLaunchKernelGGL((gemm_bt<0, ushort>), dim3(3072 / 128, 8192 / 128), dim3(256), 0, stream,
                       hbuf, WqkvT, bqkv, qkvb, 8192, 3072, 1024, (const float*)nullptr, (const float*)nullptr, 0);

    hipLaunchKernelGGL(attn_mfma, dim3(1024), dim3(256), 0, stream, qkvb, attnb);

    // x1 = x + gate_msa * (attn @ Wproj + bproj)   (gate_msa @2048)
    hipLaunchKernelGGL((gemm_bt<2, float>), dim3(1024 / 128, 8192 / 128), dim3(256), 0, stream,
                       attnb, WprojT, bproj, x1b, 8192, 1024, 1024, x, tpb, 2048);

    // LN2 + modulate (shift_mlp @3072, scale_mlp @4096)
    hipLaunchKernelGGL(ln_mod, dim3(8192), dim3(256), 0, stream, x1b, tpb, g2, be2, hbuf, 3072, 4096);

    // mid = gelu(h @ W1 + b1)
    hipLaunchKernelGGL((gemm_bt<1, ushort>), dim3(4096 / 128, 8192 / 128), dim3(256), 0, stream,
                       hbuf, W1T, b1, midb, 8192, 4096, 1024, (const float*)nullptr, (const float*)nullptr, 0);

    // out = x1 + gate_mlp * (mid @ W2 + b2)   (gate_mlp @5120)
    hipLaunchKernelGGL((gemm_bt<2, float>), dim3(1024 / 128, 8192 / 128), dim3(256), 0, stream,
                       midb, W2T, b2, (float*)d_out, 8192, 1024, 4096, x1b, tpb, 5120);
}

// Round 4
// 740.788 us; speedup vs baseline: 10.3359x; 1.2027x over previous
//
#include <hip/hip_runtime.h>
#include <hip/hip_bf16.h>
#include <math.h>

// ---------------------------------------------------------------------------
// DiT block: B=4 L=2048 D=1024 H=16 HD=64 MLP=4096.
// I/O fp32; internal bf16 MFMA, fp32 accumulate. Workspace ~164 MB (see R2).
// ---------------------------------------------------------------------------

typedef __attribute__((ext_vector_type(8))) __bf16 bf16x8;
typedef __attribute__((ext_vector_type(4))) float f32x4;

union FragU { uint4 u; bf16x8 b; };

#define AS1(p) ((const __attribute__((address_space(1))) void*)(p))
#define AS3(p) ((__attribute__((address_space(3))) void*)(p))

__device__ __forceinline__ float bflo(uint u) {
    union { uint i; float f; } v; v.i = u << 16; return v.f;
}
__device__ __forceinline__ ushort f2bf(float f) {
    union { float f; uint i; } v; v.f = f;
    uint r = (v.i + 0x7fffu + ((v.i >> 16) & 1u)) >> 16;
    return (ushort)r;
}
__device__ __forceinline__ void stval(ushort* p, float v) { *p = f2bf(v); }
__device__ __forceinline__ void stval(float* p, float v) { *p = v; }

// ---------------------------------------------------------------------------
// Transpose + fp32->bf16: in [R][C] f32 -> out [C][R] bf16.
// ---------------------------------------------------------------------------
__global__ __launch_bounds__(256) void transpose_f2b(const float* __restrict__ in,
                                                     ushort* __restrict__ out,
                                                     int R, int C) {
    __shared__ ushort t[32][33];
    int c0 = blockIdx.x * 32, r0 = blockIdx.y * 32;
    int tx = threadIdx.x, ty = threadIdx.y;  // block (32, 8)
#pragma unroll
    for (int i = 0; i < 32; i += 8)
        t[ty + i][tx] = f2bf(in[(size_t)(r0 + ty + i) * C + c0 + tx]);
    __syncthreads();
#pragma unroll
    for (int i = 0; i < 32; i += 8)
        out[(size_t)(c0 + ty + i) * R + r0 + tx] = t[tx][ty + i];
}

// ---------------------------------------------------------------------------
// tp = silu(time_emb) @ Wt + bt.  One wave per output element (b, n).
// ---------------------------------------------------------------------------
__global__ __launch_bounds__(256) void tp_gemm(const float* __restrict__ te,
                                               const ushort* __restrict__ WtT,
                                               const float* __restrict__ bt,
                                               float* __restrict__ tp) {
    int w = blockIdx.x * 4 + (threadIdx.x >> 6);
    int lane = threadIdx.x & 63;
    int b = w / 6144, n = w % 6144;
    const ushort* wr = WtT + (size_t)n * 1024;
    const float* tr = te + (size_t)b * 1024;
    float s = 0.f;
#pragma unroll
    for (int i = 0; i < 16; i++) {
        int k = lane + 64 * i;
        float t = tr[k];
        float sil = t / (1.f + __expf(-t));
        s += sil * bflo((uint)wr[k]);
    }
#pragma unroll
    for (int x = 32; x; x >>= 1) s += __shfl_xor(s, x);
    if (lane == 0) tp[(size_t)b * 6144 + n] = s + bt[n];
}

// ---------------------------------------------------------------------------
// Fused LayerNorm + AdaLN modulate: out = (ln(x)*g+be)*(1+scale)+shift.
// ---------------------------------------------------------------------------
__global__ __launch_bounds__(256) void ln_mod(const float* __restrict__ x,
                                              const float* __restrict__ tpb,
                                              const float* __restrict__ g,
                                              const float* __restrict__ be,
                                              ushort* __restrict__ out,
                                              int shift_off, int scale_off) {
    __shared__ float2 sred[4];
    int row = blockIdx.x;
    int b = row >> 11;
    int tid = threadIdx.x;
    float4 f = *(const float4*)&x[(size_t)row * 1024 + tid * 4];
    float v[4] = {f.x, f.y, f.z, f.w};
    float s = v[0] + v[1] + v[2] + v[3];
    float s2 = v[0] * v[0] + v[1] * v[1] + v[2] * v[2] + v[3] * v[3];
#pragma unroll
    for (int m = 32; m; m >>= 1) { s += __shfl_xor(s, m); s2 += __shfl_xor(s2, m); }
    if ((tid & 63) == 0) sred[tid >> 6] = make_float2(s, s2);
    __syncthreads();
    s = sred[0].x + sred[1].x + sred[2].x + sred[3].x;
    s2 = sred[0].y + sred[1].y + sred[2].y + sred[3].y;
    float mu = s * (1.f / 1024.f);
    float var = s2 * (1.f / 1024.f) - mu * mu;
    float rs = rsqrtf(var + 1e-5f);
    const float* tprow = tpb + (size_t)b * 6144;
    ushort o4[4];
#pragma unroll
    for (int t = 0; t < 4; t++) {
        int c = tid * 4 + t;
        float y = (v[t] - mu) * rs * g[c] + be[c];
        y = y * (1.f + tprow[scale_off + c]) + tprow[shift_off + c];
        o4[t] = f2bf(y);
    }
    *(uint2*)&out[(size_t)row * 1024 + tid * 4] = *(uint2*)o4;
}

// ---------------------------------------------------------------------------
// MFMA bf16 GEMM with global_load_lds staging (m97 structure).
// C[M][N] = A[M][K] @ B + bias, B transposed BT[N][K]. 128x128 tile, BK=32.
// EPI 0: +bias   EPI 1: gelu(+bias)   EPI 2: res + gate*( +bias )
// ---------------------------------------------------------------------------
template <int EPI, typename OT>
__global__ __launch_bounds__(256) void gemm_bt(const ushort* __restrict__ A,
                                               const ushort* __restrict__ BT,
                                               const float* __restrict__ bias,
                                               OT* __restrict__ C,
                                               int M, int N, int K,
                                               const float* __restrict__ res,
                                               const float* __restrict__ tpb,
                                               int goff) {
    __shared__ __align__(16) ushort As[128 * 32];
    __shared__ __align__(16) ushort Bs[128 * 32];
    int m0 = blockIdx.y * 128, n0 = blockIdx.x * 128;
    int tid = threadIdx.x;
    int wid = tid >> 6, lane = tid & 63;
    int wy = wid >> 1, wx = wid & 1;
    int r16 = lane & 15;
    int q8 = (lane >> 4) << 3;

    f32x4 acc[4][4];
#pragma unroll
    for (int i = 0; i < 4; i++)
#pragma unroll
        for (int j = 0; j < 4; j++) acc[i][j] = (f32x4){0.f, 0.f, 0.f, 0.f};

    int sr = tid >> 2;            // 0..63
    int sc = (tid & 3) << 3;      // 0,8,16,24
    const ushort* Abase = A + (size_t)(m0 + sr) * K + sc;
    const ushort* Bbase = BT + (size_t)(n0 + sr) * K + sc;
    // LDS dest is lane-contiguous: offset(tid) = tid*16 B  (row stride 64 B, 4 thr/row)
    ushort* AsW = As + (size_t)wid * 512;   // 512 ushorts = 1024 B per wave
    ushort* BsW = Bs + (size_t)wid * 512;

    for (int k0 = 0; k0 < K; k0 += 32) {
        __builtin_amdgcn_global_load_lds(AS1(Abase + k0), AS3(AsW), 16, 0, 0);
        __builtin_amdgcn_global_load_lds(AS1(Abase + (size_t)64 * K + k0), AS3(AsW + 2048), 16, 0, 0);
        __builtin_amdgcn_global_load_lds(AS1(Bbase + k0), AS3(BsW), 16, 0, 0);
        __builtin_amdgcn_global_load_lds(AS1(Bbase + (size_t)64 * K + k0), AS3(BsW + 2048), 16, 0, 0);
        __syncthreads();
        FragU fa[4], fb[4];
#pragma unroll
        for (int i = 0; i < 4; i++)
            fa[i].u = *(const uint4*)&As[(wy * 64 + i * 16 + r16) * 32 + q8];
#pragma unroll
        for (int j = 0; j < 4; j++)
            fb[j].u = *(const uint4*)&Bs[(wx * 64 + j * 16 + r16) * 32 + q8];
#pragma unroll
        for (int i = 0; i < 4; i++)
#pragma unroll
            for (int j = 0; j < 4; j++)
                acc[i][j] = __builtin_amdgcn_mfma_f32_16x16x32_bf16(fa[i].b, fb[j].b, acc[i][j], 0, 0, 0);
        __syncthreads();
    }

    int q4 = (lane >> 4) << 2;
#pragma unroll
    for (int i = 0; i < 4; i++) {
#pragma unroll
        for (int j = 0; j < 4; j++) {
            int col = n0 + wx * 64 + j * 16 + r16;
            float bv = bias[col];
#pragma unroll
            for (int t = 0; t < 4; t++) {
                int row = m0 + wy * 64 + i * 16 + q4 + t;
                float v = acc[i][j][t] + bv;
                if constexpr (EPI == 1) {
                    v = 0.5f * v * (1.f + erff(v * 0.70710678118f));
                }
                if constexpr (EPI == 2) {
                    float rv = res[(size_t)row * N + col];
                    float gate = tpb[(size_t)(row >> 11) * 6144 + goff + col];
                    v = rv + gate * v;
                }
                stval(&C[(size_t)row * N + col], v);
            }
        }
    }
}

// ---------------------------------------------------------------------------
// MFMA flash attention, 64-row Q tiles. Grid: 2048 = 64 (b,h) x 32 q-tiles.
// 4 waves/block, each wave 16 q-rows. K-loop: 64-key tiles with register
// prefetch of the NEXT K/V tile issued at the top of the compute phase (so
// the compiler's vmcnt-drain at the next barrier lands after compute).
// LDS: Ks[64][72] + Vs(V^T)[64][72] + Ps[64][72] = 27 KB -> 4+ blocks/CU.
// ---------------------------------------------------------------------------
__global__ __launch_bounds__(256, 4) void attn_mfma(const ushort* __restrict__ qkv,
                                                    ushort* __restrict__ out) {
    __shared__ __align__(16) ushort Ks[64 * 72];
    __shared__ __align__(16) ushort Vs[64 * 72];
    __shared__ __align__(16) ushort Ps[64 * 72];   // Q staging in phase 0

    int tid = threadIdx.x;
    int wid = tid >> 6, lane = tid & 63;
    int r16 = lane & 15, quad = lane >> 4;
    int q8 = quad << 3, q4 = quad << 2;

    int bh = blockIdx.x >> 5;        // 0..63
    int qt = blockIdx.x & 31;        // 0..31
    int b = bh >> 4, h = bh & 15;
    const ushort* qkbase = qkv + (size_t)b * 2048 * 3072 + h * 64;

    // ---- phase 0: stage Q tile [64][64] into Ps, load wave's A-frags ----
    {
        int r = tid >> 2;                 // 0..63
        int c = (tid & 3) << 4;           // 0,16,32,48
        const ushort* qp = qkbase + (size_t)(qt * 64 + r) * 3072 + c;
        *(uint4*)&Ps[r * 72 + c] = *(const uint4*)qp;
        *(uint4*)&Ps[r * 72 + c + 8] = *(const uint4*)(qp + 8);
    }
    __syncthreads();
    FragU qa[2];
#pragma unroll
    for (int ks = 0; ks < 2; ks++)
        qa[ks].u = *(const uint4*)&Ps[(wid * 16 + r16) * 72 + ks * 32 + q8];
    // From here each wave only touches its own 16 Ps rows (wave-private).

    float m_[4], l_[4];
    f32x4 o[4];
#pragma unroll
    for (int t = 0; t < 4; t++) { m_[t] = -1e30f; l_[t] = 0.f; }
#pragma unroll
    for (int dn = 0; dn < 4; dn++) o[dn] = (f32x4){0.f, 0.f, 0.f, 0.f};

    int kr = tid >> 2;                    // 0..63
    int kc = (tid & 3) << 4;              // 0,16,32,48
    int vk = (tid & 31) << 1;             // 0,2,..,62
    int vd = (tid >> 5) << 3;             // 0,8,..,56
    const ushort* kptr = qkbase + 1024 + (size_t)kr * 3072 + kc;
    const ushort* vptr = qkbase + 2048 + (size_t)vk * 3072 + vd;

    // prefetch tile 0
    uint4 ka0 = *(const uint4*)kptr;
    uint4 ka1 = *(const uint4*)(kptr + 8);
    uint4 va0 = *(const uint4*)vptr;
    uint4 va1 = *(const uint4*)(vptr + 3072);

    for (int kt = 0; kt < 32; kt++) {
        __syncthreads();   // previous tile's LDS readers done
        *(uint4*)&Ks[kr * 72 + kc] = ka0;
        *(uint4*)&Ks[kr * 72 + kc + 8] = ka1;
        *(uint*)&Vs[(vd + 0) * 72 + vk] = (va0.x & 0xffffu) | (va1.x << 16);
        *(uint*)&Vs[(vd + 1) * 72 + vk] = (va0.x >> 16) | (va1.x & 0xffff0000u);
        *(uint*)&Vs[(vd + 2) * 72 + vk] = (va0.y & 0xffffu) | (va1.y << 16);
        *(uint*)&Vs[(vd + 3) * 72 + vk] = (va0.y >> 16) | (va1.y & 0xffff0000u);
        *(uint*)&Vs[(vd + 4) * 72 + vk] = (va0.z & 0xffffu) | (va1.z << 16);
        *(uint*)&Vs[(vd + 5) * 72 + vk] = (va0.z >> 16) | (va1.z & 0xffff0000u);
        *(uint*)&Vs[(vd + 6) * 72 + vk] = (va0.w & 0xffffu) | (va1.w << 16);
        *(uint*)&Vs[(vd + 7) * 72 + vk] = (va0.w >> 16) | (va1.w & 0xffff0000u);
        __syncthreads();

        // prefetch next tile NOW; loads complete during compute below
        if (kt < 31) {
            const ushort* kp2 = kptr + (size_t)(kt + 1) * 64 * 3072;
            const ushort* vp2 = vptr + (size_t)(kt + 1) * 64 * 3072;
            ka0 = *(const uint4*)kp2;
            ka1 = *(const uint4*)(kp2 + 8);
            va0 = *(const uint4*)vp2;
            va1 = *(const uint4*)(vp2 + 3072);
        }

        // ---- S = Q K^T (raw; softmax scale folded into exp) ----
        f32x4 s[4];
#pragma unroll
        for (int n = 0; n < 4; n++) s[n] = (f32x4){0.f, 0.f, 0.f, 0.f};
#pragma unroll
        for (int ks = 0; ks < 2; ks++) {
            FragU kb[4];
#pragma unroll
            for (int n = 0; n < 4; n++)
                kb[n].u = *(const uint4*)&Ks[(n * 16 + r16) * 72 + ks * 32 + q8];
#pragma unroll
            for (int n = 0; n < 4; n++)
                s[n] = __builtin_amdgcn_mfma_f32_16x16x32_bf16(qa[ks].b, kb[n].b, s[n], 0, 0, 0);
        }

        // ---- online softmax (rows = quad*4+t) ----
        float al[4], c_[4];
#pragma unroll
        for (int t = 0; t < 4; t++) {
            float v0 = fmaxf(fmaxf(s[0][t], s[1][t]), fmaxf(s[2][t], s[3][t]));
#pragma unroll
            for (int msk = 1; msk < 16; msk <<= 1) v0 = fmaxf(v0, __shfl_xor(v0, msk));
            float nm = fmaxf(m_[t], v0);
            al[t] = __expf((m_[t] - nm) * 0.125f);
            c_[t] = nm * 0.125f;
            m_[t] = nm;
        }
        float ps[4] = {0.f, 0.f, 0.f, 0.f};
#pragma unroll
        for (int n = 0; n < 4; n++)
#pragma unroll
            for (int t = 0; t < 4; t++) {
                float p = __expf(__fmaf_rn(s[n][t], 0.125f, -c_[t]));
                ps[t] += p;
                Ps[(wid * 16 + q4 + t) * 72 + n * 16 + r16] = f2bf(p);
            }
#pragma unroll
        for (int t = 0; t < 4; t++) {
#pragma unroll
            for (int msk = 1; msk < 16; msk <<= 1) ps[t] += __shfl_xor(ps[t], msk);
            l_[t] = l_[t] * al[t] + ps[t];
        }
#pragma unroll
        for (int dn = 0; dn < 4; dn++)
#pragma unroll
            for (int t = 0; t < 4; t++) o[dn][t] *= al[t];

        // ---- O += P V  (Ps rows wave-private: no barrier needed) ----
#pragma unroll
        for (int ks = 0; ks < 2; ks++) {
            FragU pa, vb[4];
            pa.u = *(const uint4*)&Ps[(wid * 16 + r16) * 72 + ks * 32 + q8];
#pragma unroll
            for (int dn = 0; dn < 4; dn++)
                vb[dn].u = *(const uint4*)&Vs[(dn * 16 + r16) * 72 + ks * 32 + q8];
#pragma unroll
            for (int dn = 0; dn < 4; dn++)
                o[dn] = __builtin_amdgcn_mfma_f32_16x16x32_bf16(pa.b, vb[dn].b, o[dn], 0, 0, 0);
        }
    }

    // ---- epilogue ----
    float inv[4];
#pragma unroll
    for (int t = 0; t < 4; t++) inv[t] = 1.f / l_[t];
#pragma unroll
    for (int dn = 0; dn < 4; dn++)
#pragma unroll
        for (int t = 0; t < 4; t++) {
            int row = qt * 64 + wid * 16 + q4 + t;
            out[(size_t)(b * 2048 + row) * 1024 + h * 64 + dn * 16 + r16] =
                f2bf(o[dn][t] * inv[t]);
        }
}

// ---------------------------------------------------------------------------
extern "C" void kernel_launch(void* const* d_in, const int* in_sizes, int n_in,
                              void* d_out, int out_size, void* d_ws, size_t ws_size,
                              hipStream_t stream) {
    const float* x    = (const float*)d_in[0];
    const float* te   = (const float*)d_in[1];
    const float* Wqkv = (const float*)d_in[2];
    const float* bqkv = (const float*)d_in[3];
    const float* Wproj= (const float*)d_in[4];
    const float* bproj= (const float*)d_in[5];
    const float* W1   = (const float*)d_in[6];
    const float* b1   = (const float*)d_in[7];
    const float* W2   = (const float*)d_in[8];
    const float* b2   = (const float*)d_in[9];
    const float* Wt   = (const float*)d_in[10];
    const float* bt   = (const float*)d_in[11];
    const float* g1   = (const float*)d_in[12];
    const float* be1  = (const float*)d_in[13];
    const float* g2   = (const float*)d_in[14];
    const float* be2  = (const float*)d_in[15];

    char* ws = (char*)d_ws;
    ushort* WqkvT  = (ushort*)(ws + 0);
    ushort* WprojT = (ushort*)(ws + 6291456);
    ushort* W1T    = (ushort*)(ws + 8388608);
    ushort* W2T    = (ushort*)(ws + 16777216);
    ushort* WtT    = (ushort*)(ws + 25165824);
    float*  tpb    = (float*)(ws + 37748736);
    ushort* hbuf   = (ushort*)(ws + 37847040);
    ushort* qkvb   = (ushort*)(ws + 54624256);
    ushort* midb   = (ushort*)(ws + 54624256);   // overlays qkv (dead by then)
    ushort* attnb  = (ushort*)(ws + 121733120);
    float*  x1b    = (float*)(ws + 138510336);

    dim3 tb(32, 8);
    hipLaunchKernelGGL(transpose_f2b, dim3(3072 / 32, 1024 / 32), tb, 0, stream, Wqkv, WqkvT, 1024, 3072);
    hipLaunchKernelGGL(transpose_f2b, dim3(1024 / 32, 1024 / 32), tb, 0, stream, Wproj, WprojT, 1024, 1024);
    hipLaunchKernelGGL(transpose_f2b, dim3(4096 / 32, 1024 / 32), tb, 0, stream, W1, W1T, 1024, 4096);
    hipLaunchKernelGGL(transpose_f2b, dim3(1024 / 32, 4096 / 32), tb, 0, stream, W2, W2T, 4096, 1024);
    hipLaunchKernelGGL(transpose_f2b, dim3(6144 / 32, 1024 / 32), tb, 0, stream, Wt, WtT, 1024, 6144);

    hipLaunchKernelGGL(tp_gemm, dim3(6144), dim3(256), 0, stream, te, WtT, bt, tpb);

    // LN1 + modulate (shift_msa @0, scale_msa @1024)
    hipLaunchKernelGGL(ln_mod, dim3(8192), dim3(256), 0, stream, x, tpb, g1, be1, hbuf, 0, 1024);

    // qkv = h @ Wqkv + bqkv
    hipLaunchKernelGGL((gemm_bt<0, ushort>), dim3(3072 / 128, 8192 / 128), dim3(256), 0, stream,
                       hbuf, WqkvT, bqkv, qkvb, 8192, 3072, 1024, (const float*)nullptr, (const float*)nullptr, 0);

    hipLaunchKernelGGL(attn_mfma, dim3(2048), dim3(256), 0, stream, qkvb, attnb);

    // x1 = x + gate_msa * (attn @ Wproj + bproj)   (gate_msa @2048)
    hipLaunchKernelGGL((gemm_bt<2, float>), dim3(1024 / 128, 8192 / 128), dim3(256), 0, stream,
                       attnb, WprojT, bproj, x1b, 8192, 1024, 1024, x, tpb, 2048);

    // LN2 + modulate (shift_mlp @3072, scale_mlp @4096)
    hipLaunchKernelGGL(ln_mod, dim3(8192), dim3(256), 0, stream, x1b, tpb, g2, be2, hbuf, 3072, 4096);

    // mid = gelu(h @ W1 + b1)
    hipLaunchKernelGGL((gemm_bt<1, ushort>), dim3(4096 / 128, 8192 / 128), dim3(256), 0, stream,
                       hbuf, W1T, b1, midb, 8192, 4096, 1024, (const float*)nullptr, (const float*)nullptr, 0);

    // out = x1 + gate_mlp * (mid @ W2 + b2)   (gate_mlp @5120)
    hipLaunchKernelGGL((gemm_bt<2, float>), dim3(1024 / 128, 8192 / 128), dim3(256), 0, stream,
                       midb, W2T, b2, (float*)d_out, 8192, 1024, 4096, x1b, tpb, 5120);
}

// Round 5
// 674.126 us; speedup vs baseline: 11.3580x; 1.0989x over previous
//
#include <hip/hip_runtime.h>
#include <hip/hip_bf16.h>
#include <math.h>

// ---------------------------------------------------------------------------
// DiT block: B=4 L=2048 D=1024 H=16 HD=64 MLP=4096.
// I/O fp32; internal bf16 MFMA, fp32 accumulate. Workspace ~164 MB (see R2).
// ---------------------------------------------------------------------------

typedef __attribute__((ext_vector_type(8))) __bf16 bf16x8;
typedef __attribute__((ext_vector_type(4))) float f32x4;

union FragU { uint4 u; bf16x8 b; };

#define AS1(p) ((const __attribute__((address_space(1))) void*)(p))
#define AS3(p) ((__attribute__((address_space(3))) void*)(p))

__device__ __forceinline__ float bflo(uint u) {
    union { uint i; float f; } v; v.i = u << 16; return v.f;
}
__device__ __forceinline__ ushort f2bf(float f) {
    union { float f; uint i; } v; v.f = f;
    uint r = (v.i + 0x7fffu + ((v.i >> 16) & 1u)) >> 16;
    return (ushort)r;
}
// truncating bf16 pair pack: low half <- a, high half <- b (1 v_perm_b32)
__device__ __forceinline__ uint pkbf(float a, float b) {
    return __builtin_amdgcn_perm(__float_as_uint(b), __float_as_uint(a), 0x07060302u);
}
__device__ __forceinline__ void stval(ushort* p, float v) { *p = f2bf(v); }
__device__ __forceinline__ void stval(float* p, float v) { *p = v; }

// ---------------------------------------------------------------------------
// Transpose + fp32->bf16: in [R][C] f32 -> out [C][R] bf16.
// ---------------------------------------------------------------------------
__global__ __launch_bounds__(256) void transpose_f2b(const float* __restrict__ in,
                                                     ushort* __restrict__ out,
                                                     int R, int C) {
    __shared__ ushort t[32][33];
    int c0 = blockIdx.x * 32, r0 = blockIdx.y * 32;
    int tx = threadIdx.x, ty = threadIdx.y;  // block (32, 8)
#pragma unroll
    for (int i = 0; i < 32; i += 8)
        t[ty + i][tx] = f2bf(in[(size_t)(r0 + ty + i) * C + c0 + tx]);
    __syncthreads();
#pragma unroll
    for (int i = 0; i < 32; i += 8)
        out[(size_t)(c0 + ty + i) * R + r0 + tx] = t[tx][ty + i];
}

// ---------------------------------------------------------------------------
// tp = silu(time_emb) @ Wt + bt.  One wave per output element (b, n).
// ---------------------------------------------------------------------------
__global__ __launch_bounds__(256) void tp_gemm(const float* __restrict__ te,
                                               const ushort* __restrict__ WtT,
                                               const float* __restrict__ bt,
                                               float* __restrict__ tp) {
    int w = blockIdx.x * 4 + (threadIdx.x >> 6);
    int lane = threadIdx.x & 63;
    int b = w / 6144, n = w % 6144;
    const ushort* wr = WtT + (size_t)n * 1024;
    const float* tr = te + (size_t)b * 1024;
    float s = 0.f;
#pragma unroll
    for (int i = 0; i < 16; i++) {
        int k = lane + 64 * i;
        float t = tr[k];
        float sil = t / (1.f + __expf(-t));
        s += sil * bflo((uint)wr[k]);
    }
#pragma unroll
    for (int x = 32; x; x >>= 1) s += __shfl_xor(s, x);
    if (lane == 0) tp[(size_t)b * 6144 + n] = s + bt[n];
}

// ---------------------------------------------------------------------------
// Fused LayerNorm + AdaLN modulate: out = (ln(x)*g+be)*(1+scale)+shift.
// ---------------------------------------------------------------------------
__global__ __launch_bounds__(256) void ln_mod(const float* __restrict__ x,
                                              const float* __restrict__ tpb,
                                              const float* __restrict__ g,
                                              const float* __restrict__ be,
                                              ushort* __restrict__ out,
                                              int shift_off, int scale_off) {
    __shared__ float2 sred[4];
    int row = blockIdx.x;
    int b = row >> 11;
    int tid = threadIdx.x;
    float4 f = *(const float4*)&x[(size_t)row * 1024 + tid * 4];
    float v[4] = {f.x, f.y, f.z, f.w};
    float s = v[0] + v[1] + v[2] + v[3];
    float s2 = v[0] * v[0] + v[1] * v[1] + v[2] * v[2] + v[3] * v[3];
#pragma unroll
    for (int m = 32; m; m >>= 1) { s += __shfl_xor(s, m); s2 += __shfl_xor(s2, m); }
    if ((tid & 63) == 0) sred[tid >> 6] = make_float2(s, s2);
    __syncthreads();
    s = sred[0].x + sred[1].x + sred[2].x + sred[3].x;
    s2 = sred[0].y + sred[1].y + sred[2].y + sred[3].y;
    float mu = s * (1.f / 1024.f);
    float var = s2 * (1.f / 1024.f) - mu * mu;
    float rs = rsqrtf(var + 1e-5f);
    const float* tprow = tpb + (size_t)b * 6144;
    ushort o4[4];
#pragma unroll
    for (int t = 0; t < 4; t++) {
        int c = tid * 4 + t;
        float y = (v[t] - mu) * rs * g[c] + be[c];
        y = y * (1.f + tprow[scale_off + c]) + tprow[shift_off + c];
        o4[t] = f2bf(y);
    }
    *(uint2*)&out[(size_t)row * 1024 + tid * 4] = *(uint2*)o4;
}

// ---------------------------------------------------------------------------
// MFMA bf16 GEMM with global_load_lds staging (m97 structure).
// C[M][N] = A[M][K] @ B + bias, B transposed BT[N][K]. 128x128 tile, BK=32.
// EPI 0: +bias   EPI 1: gelu(+bias)   EPI 2: res + gate*( +bias )
// ---------------------------------------------------------------------------
template <int EPI, typename OT>
__global__ __launch_bounds__(256) void gemm_bt(const ushort* __restrict__ A,
                                               const ushort* __restrict__ BT,
                                               const float* __restrict__ bias,
                                               OT* __restrict__ C,
                                               int M, int N, int K,
                                               const float* __restrict__ res,
                                               const float* __restrict__ tpb,
                                               int goff) {
    __shared__ __align__(16) ushort As[128 * 32];
    __shared__ __align__(16) ushort Bs[128 * 32];
    int m0 = blockIdx.y * 128, n0 = blockIdx.x * 128;
    int tid = threadIdx.x;
    int wid = tid >> 6, lane = tid & 63;
    int wy = wid >> 1, wx = wid & 1;
    int r16 = lane & 15;
    int q8 = (lane >> 4) << 3;

    f32x4 acc[4][4];
#pragma unroll
    for (int i = 0; i < 4; i++)
#pragma unroll
        for (int j = 0; j < 4; j++) acc[i][j] = (f32x4){0.f, 0.f, 0.f, 0.f};

    int sr = tid >> 2;            // 0..63
    int sc = (tid & 3) << 3;      // 0,8,16,24
    const ushort* Abase = A + (size_t)(m0 + sr) * K + sc;
    const ushort* Bbase = BT + (size_t)(n0 + sr) * K + sc;
    ushort* AsW = As + (size_t)wid * 512;
    ushort* BsW = Bs + (size_t)wid * 512;

    for (int k0 = 0; k0 < K; k0 += 32) {
        __builtin_amdgcn_global_load_lds(AS1(Abase + k0), AS3(AsW), 16, 0, 0);
        __builtin_amdgcn_global_load_lds(AS1(Abase + (size_t)64 * K + k0), AS3(AsW + 2048), 16, 0, 0);
        __builtin_amdgcn_global_load_lds(AS1(Bbase + k0), AS3(BsW), 16, 0, 0);
        __builtin_amdgcn_global_load_lds(AS1(Bbase + (size_t)64 * K + k0), AS3(BsW + 2048), 16, 0, 0);
        __syncthreads();
        FragU fa[4], fb[4];
#pragma unroll
        for (int i = 0; i < 4; i++)
            fa[i].u = *(const uint4*)&As[(wy * 64 + i * 16 + r16) * 32 + q8];
#pragma unroll
        for (int j = 0; j < 4; j++)
            fb[j].u = *(const uint4*)&Bs[(wx * 64 + j * 16 + r16) * 32 + q8];
#pragma unroll
        for (int i = 0; i < 4; i++)
#pragma unroll
            for (int j = 0; j < 4; j++)
                acc[i][j] = __builtin_amdgcn_mfma_f32_16x16x32_bf16(fa[i].b, fb[j].b, acc[i][j], 0, 0, 0);
        __syncthreads();
    }

    int q4 = (lane >> 4) << 2;
#pragma unroll
    for (int i = 0; i < 4; i++) {
#pragma unroll
        for (int j = 0; j < 4; j++) {
            int col = n0 + wx * 64 + j * 16 + r16;
            float bv = bias[col];
#pragma unroll
            for (int t = 0; t < 4; t++) {
                int row = m0 + wy * 64 + i * 16 + q4 + t;
                float v = acc[i][j][t] + bv;
                if constexpr (EPI == 1) {
                    v = 0.5f * v * (1.f + erff(v * 0.70710678118f));
                }
                if constexpr (EPI == 2) {
                    float rv = res[(size_t)row * N + col];
                    float gate = tpb[(size_t)(row >> 11) * 6144 + goff + col];
                    v = rv + gate * v;
                }
                stval(&C[(size_t)row * N + col], v);
            }
        }
    }
}

// ---------------------------------------------------------------------------
// MFMA flash attention, transposed-S formulation. 64-row Q tiles, grid
// 2048 = 64 (b,h) x 32 q-tiles, 4 waves x 16 q-rows.
// S^T = K Q^T (mfma args swapped; identical LDS loads) -> softmax row = C
// column = lane&15: scalar m/l per lane, in-lane key reduction + 2 shfls.
// P packed (truncating v_perm) into Ps[qrow][key] wave-private rows, then
// O^T = V^T P^T (again just swapped operands).
// LDS: Ks[64][72] + Vs[64][72] + Ps[64][72] = 27 KB.
// ---------------------------------------------------------------------------
__global__ __launch_bounds__(256, 4) void attn_mfma(const ushort* __restrict__ qkv,
                                                    ushort* __restrict__ out) {
    __shared__ __align__(16) ushort Ks[64 * 72];
    __shared__ __align__(16) ushort Vs[64 * 72];
    __shared__ __align__(16) ushort Ps[64 * 72];   // Q staging in phase 0

    int tid = threadIdx.x;
    int wid = tid >> 6, lane = tid & 63;
    int r16 = lane & 15, quad = lane >> 4;
    int q8 = quad << 3, q4 = quad << 2;

    int bh = blockIdx.x >> 5;        // 0..63
    int qt = blockIdx.x & 31;        // 0..31
    int b = bh >> 4, h = bh & 15;
    const ushort* qkbase = qkv + (size_t)b * 2048 * 3072 + h * 64;

    // ---- phase 0: stage Q tile [64][64] into Ps, load wave's Q frags ----
    {
        int r = tid >> 2;                 // 0..63
        int c = (tid & 3) << 4;           // 0,16,32,48
        const ushort* qp = qkbase + (size_t)(qt * 64 + r) * 3072 + c;
        *(uint4*)&Ps[r * 72 + c] = *(const uint4*)qp;
        *(uint4*)&Ps[r * 72 + c + 8] = *(const uint4*)(qp + 8);
    }
    __syncthreads();
    FragU qa[2];
#pragma unroll
    for (int ks = 0; ks < 2; ks++)
        qa[ks].u = *(const uint4*)&Ps[(wid * 16 + r16) * 72 + ks * 32 + q8];
    // From here each wave only touches its own 16 Ps rows (wave-private).

    float m_ = -1e30f, l_ = 0.f;          // scalars: this lane's q-row = r16
    f32x4 o[4];
#pragma unroll
    for (int dn = 0; dn < 4; dn++) o[dn] = (f32x4){0.f, 0.f, 0.f, 0.f};

    int kr = tid >> 2;                    // 0..63
    int kc = (tid & 3) << 4;              // 0,16,32,48
    int vk = (tid & 31) << 1;             // 0,2,..,62
    int vd = (tid >> 5) << 3;             // 0,8,..,56
    const ushort* kptr = qkbase + 1024 + (size_t)kr * 3072 + kc;
    const ushort* vptr = qkbase + 2048 + (size_t)vk * 3072 + vd;

    // prefetch tile 0
    uint4 ka0 = *(const uint4*)kptr;
    uint4 ka1 = *(const uint4*)(kptr + 8);
    uint4 va0 = *(const uint4*)vptr;
    uint4 va1 = *(const uint4*)(vptr + 3072);

    for (int kt = 0; kt < 32; kt++) {
        __syncthreads();   // previous tile's LDS readers done
        *(uint4*)&Ks[kr * 72 + kc] = ka0;
        *(uint4*)&Ks[kr * 72 + kc + 8] = ka1;
        *(uint*)&Vs[(vd + 0) * 72 + vk] = (va0.x & 0xffffu) | (va1.x << 16);
        *(uint*)&Vs[(vd + 1) * 72 + vk] = (va0.x >> 16) | (va1.x & 0xffff0000u);
        *(uint*)&Vs[(vd + 2) * 72 + vk] = (va0.y & 0xffffu) | (va1.y << 16);
        *(uint*)&Vs[(vd + 3) * 72 + vk] = (va0.y >> 16) | (va1.y & 0xffff0000u);
        *(uint*)&Vs[(vd + 4) * 72 + vk] = (va0.z & 0xffffu) | (va1.z << 16);
        *(uint*)&Vs[(vd + 5) * 72 + vk] = (va0.z >> 16) | (va1.z & 0xffff0000u);
        *(uint*)&Vs[(vd + 6) * 72 + vk] = (va0.w & 0xffffu) | (va1.w << 16);
        *(uint*)&Vs[(vd + 7) * 72 + vk] = (va0.w >> 16) | (va1.w & 0xffff0000u);
        __syncthreads();

        // prefetch next tile; loads complete during compute below
        if (kt < 31) {
            const ushort* kp2 = kptr + (size_t)(kt + 1) * 64 * 3072;
            const ushort* vp2 = vptr + (size_t)(kt + 1) * 64 * 3072;
            ka0 = *(const uint4*)kp2;
            ka1 = *(const uint4*)(kp2 + 8);
            va0 = *(const uint4*)vp2;
            va1 = *(const uint4*)(vp2 + 3072);
        }

        // ---- S^T = K Q^T  (lane holds keys n*16+q4+t for q-row r16) ----
        f32x4 s[4];
#pragma unroll
        for (int n = 0; n < 4; n++) s[n] = (f32x4){0.f, 0.f, 0.f, 0.f};
#pragma unroll
        for (int ks = 0; ks < 2; ks++) {
            FragU kb[4];
#pragma unroll
            for (int n = 0; n < 4; n++)
                kb[n].u = *(const uint4*)&Ks[(n * 16 + r16) * 72 + ks * 32 + q8];
#pragma unroll
            for (int n = 0; n < 4; n++)
                s[n] = __builtin_amdgcn_mfma_f32_16x16x32_bf16(kb[n].b, qa[ks].b, s[n], 0, 0, 0);
        }

        // ---- online softmax: scalar per lane, keys in-lane + across quads ----
        float mx = fmaxf(fmaxf(fmaxf(s[0][0], s[0][1]), fmaxf(s[0][2], s[0][3])),
                         fmaxf(fmaxf(s[1][0], s[1][1]), fmaxf(s[1][2], s[1][3])));
        mx = fmaxf(mx, fmaxf(fmaxf(fmaxf(s[2][0], s[2][1]), fmaxf(s[2][2], s[2][3])),
                             fmaxf(fmaxf(s[3][0], s[3][1]), fmaxf(s[3][2], s[3][3]))));
        mx = fmaxf(mx, __shfl_xor(mx, 16));
        mx = fmaxf(mx, __shfl_xor(mx, 32));
        float nm = fmaxf(m_, mx);
        float al = __expf((m_ - nm) * 0.125f);
        float cc = nm * 0.125f;
        m_ = nm;

        float p[4][4];
        float ps = 0.f;
#pragma unroll
        for (int n = 0; n < 4; n++)
#pragma unroll
            for (int t = 0; t < 4; t++) {
                p[n][t] = __expf(__fmaf_rn(s[n][t], 0.125f, -cc));
                ps += p[n][t];
            }
        ps += __shfl_xor(ps, 16);
        ps += __shfl_xor(ps, 32);
        l_ = l_ * al + ps;
#pragma unroll
        for (int dn = 0; dn < 4; dn++)
#pragma unroll
            for (int t = 0; t < 4; t++) o[dn][t] *= al;

        // ---- P -> Ps[qrow=r16][key] (wave-private rows, 4x b64 writes) ----
#pragma unroll
        for (int n = 0; n < 4; n++) {
            uint2 w2 = make_uint2(pkbf(p[n][0], p[n][1]), pkbf(p[n][2], p[n][3]));
            *(uint2*)&Ps[(wid * 16 + r16) * 72 + n * 16 + q4] = w2;
        }

        // ---- O^T += V^T P^T  (same vb/pa reads as before, swapped args) ----
#pragma unroll
        for (int ks = 0; ks < 2; ks++) {
            FragU pa, vb[4];
            pa.u = *(const uint4*)&Ps[(wid * 16 + r16) * 72 + ks * 32 + q8];
#pragma unroll
            for (int dn = 0; dn < 4; dn++)
                vb[dn].u = *(const uint4*)&Vs[(dn * 16 + r16) * 72 + ks * 32 + q8];
#pragma unroll
            for (int dn = 0; dn < 4; dn++)
                o[dn] = __builtin_amdgcn_mfma_f32_16x16x32_bf16(vb[dn].b, pa.b, o[dn], 0, 0, 0);
        }
    }

    // ---- epilogue: lane holds O^T[d=dn*16+q4+t][qrow=r16] ----
    float inv = 1.f / l_;
    int row = qt * 64 + wid * 16 + r16;
    ushort* orow = out + (size_t)(b * 2048 + row) * 1024 + h * 64;
#pragma unroll
    for (int dn = 0; dn < 4; dn++) {
        uint2 w2 = make_uint2(pkbf(o[dn][0] * inv, o[dn][1] * inv),
                              pkbf(o[dn][2] * inv, o[dn][3] * inv));
        *(uint2*)&orow[dn * 16 + q4] = w2;
    }
}

// ---------------------------------------------------------------------------
extern "C" void kernel_launch(void* const* d_in, const int* in_sizes, int n_in,
                              void* d_out, int out_size, void* d_ws, size_t ws_size,
                              hipStream_t stream) {
    const float* x    = (const float*)d_in[0];
    const float* te   = (const float*)d_in[1];
    const float* Wqkv = (const float*)d_in[2];
    const float* bqkv = (const float*)d_in[3];
    const float* Wproj= (const float*)d_in[4];
    const float* bproj= (const float*)d_in[5];
    const float* W1   = (const float*)d_in[6];
    const float* b1   = (const float*)d_in[7];
    const float* W2   = (const float*)d_in[8];
    const float* b2   = (const float*)d_in[9];
    const float* Wt   = (const float*)d_in[10];
    const float* bt   = (const float*)d_in[11];
    const float* g1   = (const float*)d_in[12];
    const float* be1  = (const float*)d_in[13];
    const float* g2   = (const float*)d_in[14];
    const float* be2  = (const float*)d_in[15];

    char* ws = (char*)d_ws;
    ushort* WqkvT  = (ushort*)(ws + 0);
    ushort* WprojT = (ushort*)(ws + 6291456);
    ushort* W1T    = (ushort*)(ws + 8388608);
    ushort* W2T    = (ushort*)(ws + 16777216);
    ushort* WtT    = (ushort*)(ws + 25165824);
    float*  tpb    = (float*)(ws + 37748736);
    ushort* hbuf   = (ushort*)(ws + 37847040);
    ushort* qkvb   = (ushort*)(ws + 54624256);
    ushort* midb   = (ushort*)(ws + 54624256);   // overlays qkv (dead by then)
    ushort* attnb  = (ushort*)(ws + 121733120);
    float*  x1b    = (float*)(ws + 138510336);

    dim3 tb(32, 8);
    hipLaunchKernelGGL(transpose_f2b, dim3(3072 / 32, 1024 / 32), tb, 0, stream, Wqkv, WqkvT, 1024, 3072);
    hipLaunchKernelGGL(transpose_f2b, dim3(1024 / 32, 1024 / 32), tb, 0, stream, Wproj, WprojT, 1024, 1024);
    hipLaunchKernelGGL(transpose_f2b, dim3(4096 / 32, 1024 / 32), tb, 0, stream, W1, W1T, 1024, 4096);
    hipLaunchKernelGGL(transpose_f2b, dim3(1024 / 32, 4096 / 32), tb, 0, stream, W2, W2T, 4096, 1024);
    hipLaunchKernelGGL(transpose_f2b, dim3(6144 / 32, 1024 / 32), tb, 0, stream, Wt, WtT, 1024, 6144);

    hipLaunchKernelGGL(tp_gemm, dim3(6144), dim3(256), 0, stream, te, WtT, bt, tpb);

    // LN1 + modulate (shift_msa @0, scale_msa @1024)
    hipLaunchKernelGGL(ln_mod, dim3(8192), dim3(256), 0, stream, x, tpb, g1, be1, hbuf, 0, 1024);

    // qkv = h @ Wqkv + bqkv
    hipLaunchKernelGGL((gemm_bt<0, ushort>), dim3(3072 / 128, 8192 / 128), dim3(256), 0, stream,
                       hbuf, WqkvT, bqkv, qkvb, 8192, 3072, 1024, (const float*)nullptr, (const float*)nullptr, 0);

    hipLaunchKernelGGL(attn_mfma, dim3(2048), dim3(256), 0, stream, qkvb, attnb);

    // x1 = x + gate_msa * (attn @ Wproj + bproj)   (gate_msa @2048)
    hipLaunchKernelGGL((gemm_bt<2, float>), dim3(1024 / 128, 8192 / 128), dim3(256), 0, stream,
                       attnb, WprojT, bproj, x1b, 8192, 1024, 1024, x, tpb, 2048);

    // LN2 + modulate (shift_mlp @3072, scale_mlp @4096)
    hipLaunchKernelGGL(ln_mod, dim3(8192), dim3(256), 0, stream, x1b, tpb, g2, be2, hbuf, 3072, 4096);

    // mid = gelu(h @ W1 + b1)
    hipLaunchKernelGGL((gemm_bt<1, ushort>), dim3(4096 / 128, 8192 / 128), dim3(256), 0, stream,
                       hbuf, W1T, b1, midb, 8192, 4096, 1024, (const float*)nullptr, (const float*)nullptr, 0);

    // out = x1 + gate_mlp * (mid @ W2 + b2)   (gate_mlp @5120)
    hipLaunchKernelGGL((gemm_bt<2, float>), dim3(1024 / 128, 8192 / 128), dim3(256), 0, stream,
                       midb, W2T, b2, (float*)d_out, 8192, 1024, 4096, x1b, tpb, 5120);
}